// Round 3
// baseline (305.109 us; speedup 1.0000x reference)
//
#include <hip/hip_runtime.h>
#include <hip/hip_bf16.h>
#include <cstdint>

#define NROWS 262144
#define DIM 128

typedef float f32x4 __attribute__((ext_vector_type(4)));
typedef short s16x8 __attribute__((ext_vector_type(8)));
typedef unsigned short u16x8 __attribute__((ext_vector_type(8)));
typedef unsigned int u32x4 __attribute__((ext_vector_type(4)));

__device__ __forceinline__ unsigned short cvbf(float f){
  unsigned u = __float_as_uint(f);
  return (unsigned short)((u + 0x8000u) >> 16);
}

__device__ __forceinline__ void ldsload16(const void* gp, void* lp){
  __builtin_amdgcn_global_load_lds((const __attribute__((address_space(1))) void*)gp,
                                   (__attribute__((address_space(3))) void*)lp,
                                   16, 0, 0);
}

// ---------------- prep kernel: weight repack + dtype detect into d_ws ----------------
// ws[0..65536): W1T bf16, row n=g*64+h (256 x 256B), byte = n*256 + (k*2 ^ ((n&7)<<4))
// ws[65536..73728): W2T bf16, row t=g*16+p (64 x 128B); element slot e (=ks*32+q*8+j)
//   holds W2[g][h(e)][p], h(e) = (e&32)|((e&4)<<2)|((e>>1)&12)|(e&3)   (k-slot permutation
//   matching the GEMM1 C^T fragment layout so GEMM2 needs NO hidden transpose), p>=4 zeros.
//   byte = t*128 + ((e*2) ^ ((t&7)<<4))
// ws[73728]: gshift (0=int32 gids, 1=int64) ; ws[73732]: mshift (0=byte mask, 2=int32 mask)
__global__ void prep_kernel(const float* __restrict__ W1, const float* __restrict__ W2,
                            const void* __restrict__ gids_raw, const void* __restrict__ mask_raw,
                            unsigned char* __restrict__ ws){
  int tid = threadIdx.x, bid = blockIdx.x;
  if (bid < 16){
    int chunk = bid*256 + tid;
    int n    = chunk >> 4;
    int kb16 = chunk & 15;
    int d0   = kb16 * 8;
    int g = n >> 6, h = n & 63;
    u16x8 v;
#pragma unroll
    for (int j=0;j<8;++j) v[j] = cvbf(W1[((g*DIM) + d0 + j)*64 + h]);
    unsigned off = (unsigned)n*256 + (((unsigned)kb16*16) ^ (((unsigned)(n&7))<<4));
    *(u16x8*)(ws + off) = v;
  } else {
#pragma unroll
    for (int i=0;i<16;++i){
      int el = tid + i*256;          // 0..4095 elements of W2T
      int t  = el >> 6;              // row t = g*16+p
      int e  = el & 63;              // k-slot within row
      int g = t >> 4, p = t & 15;
      int h = (e & 32) | ((e & 4) << 2) | ((e >> 1) & 12) | (e & 3);
      float f = (p < 4) ? W2[(g*64 + h)*4 + p] : 0.0f;
      unsigned off = 65536u + (unsigned)t*128 + (((unsigned)(e*2)) ^ (((unsigned)(t&7))<<4));
      *(unsigned short*)(ws + off) = cvbf(f);
    }
    if (tid < 64){
      const int* g32 = (const int*)gids_raw;
      int accg = 0;
#pragma unroll
      for (int i=0;i<8;++i) accg |= g32[(tid*8 + i)*2 + 1];
      const unsigned char* m8 = (const unsigned char*)mask_raw;
      int accm = 0;
#pragma unroll
      for (int i=0;i<16;++i){
        int off = tid*16 + i;
        if (off & 3) accm |= m8[off];
      }
      unsigned long long bg = __ballot(accg != 0);
      unsigned long long bm = __ballot(accm != 0);
      if (tid == 0){
        *(int*)(ws + 73728) = (bg == 0ull) ? 1 : 0;
        *(int*)(ws + 73732) = (bm == 0ull) ? 2 : 0;
      }
    }
  }
}

// ---------------- main kernel: persistent, barrier-free main loop ----------------
#define LDS_W2T 65536
#define LDS_B1  (65536+8192)
#define LDS_TOTAL (65536+8192+1024)

__global__ __launch_bounds__(256, 2)
void actor_kernel(const float* __restrict__ X, const int* __restrict__ gids,
                  const unsigned char* __restrict__ fmask,
                  const float* __restrict__ b1, const float* __restrict__ b2,
                  const unsigned char* __restrict__ ws, float* __restrict__ out){
  __shared__ char smem[LDS_TOTAL];
  const int tid  = threadIdx.x;
  const int wave = tid >> 6, lane = tid & 63;
  const int q    = lane >> 4, rS = lane & 15;
  const int swzA = (rS & 7) << 4;

  const int gshift = *(const int*)(ws + 73728);
  const int mshift = *(const int*)(ws + 73732);

  // --- stage weights+b1 to LDS once per block ---
#pragma unroll
  for (int i=0;i<16;++i){
    int off = i*4096 + wave*1024;
    ldsload16(ws + off + lane*16, smem + off);
  }
#pragma unroll
  for (int i=0;i<2;++i){
    int off = i*4096 + wave*1024;
    ldsload16(ws + 65536 + off + lane*16, smem + LDS_W2T + off);
  }
  if (wave == 0)
    ldsload16((const unsigned char*)b1 + lane*16, smem + LDS_B1);

  const long base = (long)blockIdx.x * 512 + wave * 32;   // this wave's first row

  f32x4 xb[2][4][2];     // X single register buffer [nt][k][half]
  int   gb[2];
  u32x4 mb[2];

  auto loadX = [&](int t, int nt){
    const float* xp = X + (base + t*128 + nt*16 + rS) * DIM + q*8;
#pragma unroll
    for (int k=0;k<4;++k){
      xb[nt][k][0] = *(const f32x4*)(xp + k*32);
      xb[nt][k][1] = *(const f32x4*)(xp + k*32 + 4);
    }
  };
  auto pf_gm = [&](int t){
    if (q == 0){
#pragma unroll
      for (int nt=0;nt<2;++nt){
        long row = base + t*128 + nt*16 + rS;
        gb[nt] = gids[(size_t)row << gshift];
        if (mshift) mb[nt] = *(const u32x4*)(fmask + row*16);
        else        mb[nt][0] = *(const unsigned*)(fmask + row*4);
      }
    }
  };

  loadX(0,0); loadX(0,1); pf_gm(0);
  __syncthreads();   // weights resident (drains all outstanding loads too)

  const f32x4 z = (f32x4){0.f,0.f,0.f,0.f};

#pragma unroll 1
  for (int t=0;t<4;++t){
    const long row0 = base + t*128;

    // --- convert current X to bf16 B-fragments ---
    s16x8 bfr[2][4];
#pragma unroll
    for (int nt=0;nt<2;++nt)
#pragma unroll
      for (int k=0;k<4;++k){
        s16x8 v;
#pragma unroll
        for (int j=0;j<4;++j){ v[j] = (short)cvbf(xb[nt][k][0][j]); v[j+4] = (short)cvbf(xb[nt][k][1][j]); }
        bfr[nt][k] = v;
      }

    // --- prefetch next tile, first half (regs just freed by cvt) ---
    if (t < 3) loadX(t+1, 0);

    // --- GEMM1: C^T = W1T x X^T ---
    f32x4 acc[16][2];
#pragma unroll
    for (int mt=0;mt<16;++mt){
      const s16x8 a = *(const s16x8*)(smem + (mt*16 + rS)*256 + ((q*16) ^ swzA));
      acc[mt][0] = __builtin_amdgcn_mfma_f32_16x16x32_bf16(a, bfr[0][0], z, 0,0,0);
      acc[mt][1] = __builtin_amdgcn_mfma_f32_16x16x32_bf16(a, bfr[1][0], z, 0,0,0);
    }
#pragma unroll
    for (int k=1;k<4;++k)
#pragma unroll
      for (int mt=0;mt<16;++mt){
        const s16x8 a = *(const s16x8*)(smem + (mt*16 + rS)*256 + ((k*64 + q*16) ^ swzA));
        acc[mt][0] = __builtin_amdgcn_mfma_f32_16x16x32_bf16(a, bfr[0][k], acc[mt][0], 0,0,0);
        acc[mt][1] = __builtin_amdgcn_mfma_f32_16x16x32_bf16(a, bfr[1][k], acc[mt][1], 0,0,0);
      }

    // --- epilogue1: +b1, relu, pack to bf16 pairs (stays in registers!) ---
    unsigned hc[2][16][2];
#pragma unroll
    for (int mt=0;mt<16;++mt){
      const f32x4 b1v = *(const f32x4*)(smem + LDS_B1 + mt*64 + q*16);
#pragma unroll
      for (int nt=0;nt<2;++nt){
        f32x4 v = acc[mt][nt] + b1v;
#pragma unroll
        for (int j=0;j<4;++j) v[j] = v[j] > 0.f ? v[j] : 0.f;
        hc[nt][mt][0] = (unsigned)cvbf(v[0]) | ((unsigned)cvbf(v[1])<<16);
        hc[nt][mt][1] = (unsigned)cvbf(v[2]) | ((unsigned)cvbf(v[3])<<16);
      }
    }

    // --- prefetch next tile, second half ---
    if (t < 3) loadX(t+1, 1);

    // --- GEMM2: logits^T = W2T x hidden^T ; B-frags are the lane's own hc regs ---
    f32x4 acc2[4][2];
#pragma unroll
    for (int g=0;g<4;++g)
#pragma unroll
      for (int ks=0;ks<2;++ks){
        const s16x8 af = *(const s16x8*)(smem + LDS_W2T + (g*16 + rS)*128 + ((ks*64 + q*16) ^ swzA));
#pragma unroll
        for (int nt=0;nt<2;++nt){
          union { u32x4 u; s16x8 s; } hf;
          hf.u = (u32x4){ hc[nt][4*g+2*ks][0], hc[nt][4*g+2*ks][1],
                          hc[nt][4*g+2*ks+1][0], hc[nt][4*g+2*ks+1][1] };
          acc2[g][nt] = __builtin_amdgcn_mfma_f32_16x16x32_bf16(
              af, hf.s, (ks==0) ? z : acc2[g][nt], 0,0,0);
        }
      }

    // --- epilogue2: lane q==0 holds a full row's 4 logits -> lane-local softmax ---
    if (q == 0){
#pragma unroll
      for (int nt=0;nt<2;++nt){
        long row = row0 + nt*16 + rS;
        int g = gb[nt];
        f32x4 lv = acc2[0][nt];
        lv = (g==1) ? acc2[1][nt] : lv;
        lv = (g==2) ? acc2[2][nt] : lv;
        lv = (g==3) ? acc2[3][nt] : lv;
        f32x4 bs = *(const f32x4*)(b2);
        bs = (g==1) ? *(const f32x4*)(b2+4)  : bs;
        bs = (g==2) ? *(const f32x4*)(b2+8)  : bs;
        bs = (g==3) ? *(const f32x4*)(b2+12) : bs;
        f32x4 li;
#pragma unroll
        for (int p=0;p<4;++p){
          unsigned fe = mshift ? mb[nt][p] : ((mb[nt][0] >> (8*p)) & 0xffu);
          li[p] = fe ? (lv[p] + bs[p]) : -1e9f;
        }
        float m = fmaxf(fmaxf(li[0],li[1]), fmaxf(li[2],li[3]));
        f32x4 e;
#pragma unroll
        for (int p=0;p<4;++p) e[p] = __expf(li[p] - m);
        float inv = 1.0f / (e[0]+e[1]+e[2]+e[3]);
        f32x4 o;
#pragma unroll
        for (int p=0;p<4;++p) o[p] = e[p] * inv;
        *(f32x4*)(out + row*4) = o;
      }
    }

    // --- prefetch gids/mask for next tile (after epilogue2 consumed current) ---
    if (t < 3) pf_gm(t+1);
  }
}

extern "C" void kernel_launch(void* const* d_in, const int* in_sizes, int n_in,
                              void* d_out, int out_size, void* d_ws, size_t ws_size,
                              hipStream_t stream){
  const float* X  = (const float*)d_in[0];
  const void*  gi = d_in[1];
  const void*  fm = d_in[2];
  const float* W1 = (const float*)d_in[3];
  const float* b1 = (const float*)d_in[4];
  const float* W2 = (const float*)d_in[5];
  const float* b2 = (const float*)d_in[6];
  unsigned char* ws = (unsigned char*)d_ws;
  float* out = (float*)d_out;

  prep_kernel<<<dim3(17), dim3(256), 0, stream>>>(W1, W2, gi, fm, ws);
  actor_kernel<<<dim3(512), dim3(256), 0, stream>>>(X, (const int*)gi,
                                                    (const unsigned char*)fm,
                                                    b1, b2, ws, out);
}

// Round 4
// 214.412 us; speedup vs baseline: 1.4230x; 1.4230x over previous
//
#include <hip/hip_runtime.h>
#include <hip/hip_bf16.h>
#include <cstdint>

#define NROWS 262144
#define DIM 128

typedef float f32x4 __attribute__((ext_vector_type(4)));
typedef short s16x8 __attribute__((ext_vector_type(8)));
typedef unsigned short u16x8 __attribute__((ext_vector_type(8)));
typedef unsigned int u32x4 __attribute__((ext_vector_type(4)));

__device__ __forceinline__ unsigned short cvbf(float f){
  unsigned u = __float_as_uint(f);
  return (unsigned short)((u + 0x8000u) >> 16);
}

__device__ __forceinline__ void ldsload16(const void* gp, void* lp){
  __builtin_amdgcn_global_load_lds((const __attribute__((address_space(1))) void*)gp,
                                   (__attribute__((address_space(3))) void*)lp,
                                   16, 0, 0);
}

// ---------------- prep kernel: weight repack + dtype detect into d_ws ----------------
// ws[0..65536): W1T bf16, row n=g*64+h (256 x 256B), byte = n*256 + (k*2 ^ ((n&7)<<4))
// ws[65536..73728): W2T bf16, row t=g*16+p (64 x 128B); element slot e (=ks*32+q*8+j)
//   holds W2[g][h(e)][p], h(e) = (e&32)|((e&4)<<2)|((e>>1)&12)|(e&3)  (k-slot permutation
//   matching GEMM1's C^T fragment layout -> GEMM2 needs no hidden transpose), p>=4 zeros.
// ws[73728]: gshift (0=int32 gids, 1=int64) ; ws[73732]: mshift (0=byte mask, 2=int32 mask)
__global__ void prep_kernel(const float* __restrict__ W1, const float* __restrict__ W2,
                            const void* __restrict__ gids_raw, const void* __restrict__ mask_raw,
                            unsigned char* __restrict__ ws){
  int tid = threadIdx.x, bid = blockIdx.x;
  if (bid < 16){
    int chunk = bid*256 + tid;
    int n    = chunk >> 4;
    int kb16 = chunk & 15;
    int d0   = kb16 * 8;
    int g = n >> 6, h = n & 63;
    u16x8 v;
#pragma unroll
    for (int j=0;j<8;++j) v[j] = cvbf(W1[((g*DIM) + d0 + j)*64 + h]);
    unsigned off = (unsigned)n*256 + (((unsigned)kb16*16) ^ (((unsigned)(n&7))<<4));
    *(u16x8*)(ws + off) = v;
  } else {
#pragma unroll
    for (int i=0;i<16;++i){
      int el = tid + i*256;          // 0..4095 elements of W2T
      int t  = el >> 6;              // row t = g*16+p
      int e  = el & 63;              // k-slot within row
      int g = t >> 4, p = t & 15;
      int h = (e & 32) | ((e & 4) << 2) | ((e >> 1) & 12) | (e & 3);
      float f = (p < 4) ? W2[(g*64 + h)*4 + p] : 0.0f;
      unsigned off = 65536u + (unsigned)t*128 + (((unsigned)(e*2)) ^ (((unsigned)(t&7))<<4));
      *(unsigned short*)(ws + off) = cvbf(f);
    }
    if (tid < 64){
      const int* g32 = (const int*)gids_raw;
      int accg = 0;
#pragma unroll
      for (int i=0;i<8;++i) accg |= g32[(tid*8 + i)*2 + 1];
      const unsigned char* m8 = (const unsigned char*)mask_raw;
      int accm = 0;
#pragma unroll
      for (int i=0;i<16;++i){
        int off = tid*16 + i;
        if (off & 3) accm |= m8[off];
      }
      unsigned long long bg = __ballot(accg != 0);
      unsigned long long bm = __ballot(accm != 0);
      if (tid == 0){
        *(int*)(ws + 73728) = (bg == 0ull) ? 1 : 0;
        *(int*)(ws + 73732) = (bm == 0ull) ? 2 : 0;
      }
    }
  }
}

// ---------------- main kernel: persistent, 16 rows/wave/iter, barrier-free loop ----------------
#define LDS_W2T 65536
#define LDS_B1  (65536+8192)
#define LDS_TOTAL (65536+8192+1024)

__global__ __launch_bounds__(256, 2)
void actor_kernel(const float* __restrict__ X, const int* __restrict__ gids,
                  const unsigned char* __restrict__ fmask,
                  const float* __restrict__ b1, const float* __restrict__ b2,
                  const unsigned char* __restrict__ ws, float* __restrict__ out){
  __shared__ char smem[LDS_TOTAL];
  const int tid  = threadIdx.x;
  const int wave = tid >> 6, lane = tid & 63;
  const int q    = lane >> 4, rS = lane & 15;
  const int swzA = (rS & 7) << 4;

  const int gshift = *(const int*)(ws + 73728);
  const int mshift = *(const int*)(ws + 73732);

  // --- stage weights+b1 to LDS once per block ---
#pragma unroll
  for (int i=0;i<16;++i){
    int off = i*4096 + wave*1024;
    ldsload16(ws + off + lane*16, smem + off);
  }
#pragma unroll
  for (int i=0;i<2;++i){
    int off = i*4096 + wave*1024;
    ldsload16(ws + 65536 + off + lane*16, smem + LDS_W2T + off);
  }
  if (wave == 0)
    ldsload16((const unsigned char*)b1 + lane*16, smem + LDS_B1);

  const long base = (long)blockIdx.x * 512 + wave * 128;   // this wave's first row

  f32x4 xb[4][2];    // single-buffered X registers for one 16-row unit
  int   gb;
  u32x4 mb;

  // prologue: unit 0 loads
  {
    const float* xp = X + (base + rS) * DIM + q*8;
#pragma unroll
    for (int k=0;k<4;++k){
      xb[k][0] = *(const f32x4*)(xp + k*32);
      xb[k][1] = *(const f32x4*)(xp + k*32 + 4);
    }
    if (q == 0){
      long row = base + rS;
      gb = gids[(size_t)row << gshift];
      if (mshift) mb = *(const u32x4*)(fmask + row*16);
      else        mb[0] = *(const unsigned*)(fmask + row*4);
    }
  }
  __syncthreads();   // weights resident

  const f32x4 z = (f32x4){0.f,0.f,0.f,0.f};

#pragma unroll 1
  for (int u=0; u<8; ++u){
    // --- convert current unit's X to bf16 B-fragments (frees xb for prefetch) ---
    s16x8 bfr[4];
#pragma unroll
    for (int k=0;k<4;++k){
      s16x8 v;
#pragma unroll
      for (int j=0;j<4;++j){ v[j] = (short)cvbf(xb[k][0][j]); v[j+4] = (short)cvbf(xb[k][1][j]); }
      bfr[k] = v;
    }

    // --- prefetch next unit's X (in flight across GEMM1+GEMM2) ---
    if (u < 7){
      const float* xp = X + (base + (u+1)*16 + rS) * DIM + q*8;
#pragma unroll
      for (int k=0;k<4;++k){
        xb[k][0] = *(const f32x4*)(xp + k*32);
        xb[k][1] = *(const f32x4*)(xp + k*32 + 4);
      }
    }

    // --- GEMM1: C^T = W1T x X^T  (M = 256 hidden cols, N = 16 rows) ---
    f32x4 acc[16];
#pragma unroll
    for (int mt=0;mt<16;++mt){
      const s16x8 a = *(const s16x8*)(smem + (mt*16 + rS)*256 + ((q*16) ^ swzA));
      acc[mt] = __builtin_amdgcn_mfma_f32_16x16x32_bf16(a, bfr[0], z, 0,0,0);
    }
#pragma unroll
    for (int k=1;k<4;++k)
#pragma unroll
      for (int mt=0;mt<16;++mt){
        const s16x8 a = *(const s16x8*)(smem + (mt*16 + rS)*256 + ((k*64 + q*16) ^ swzA));
        acc[mt] = __builtin_amdgcn_mfma_f32_16x16x32_bf16(a, bfr[k], acc[mt], 0,0,0);
      }

    // --- epilogue1: +b1, relu, pack to bf16 pairs (registers only) ---
    unsigned hc[16][2];
#pragma unroll
    for (int mt=0;mt<16;++mt){
      const f32x4 b1v = *(const f32x4*)(smem + LDS_B1 + mt*64 + q*16);
      f32x4 v = acc[mt] + b1v;
#pragma unroll
      for (int j=0;j<4;++j) v[j] = v[j] > 0.f ? v[j] : 0.f;
      hc[mt][0] = (unsigned)cvbf(v[0]) | ((unsigned)cvbf(v[1])<<16);
      hc[mt][1] = (unsigned)cvbf(v[2]) | ((unsigned)cvbf(v[3])<<16);
    }

    // --- GEMM2: logits^T = W2T x hidden^T ; B-frags are the lane's own hc regs ---
    f32x4 acc2[4];
#pragma unroll
    for (int g=0;g<4;++g)
#pragma unroll
      for (int ks=0;ks<2;++ks){
        const s16x8 af = *(const s16x8*)(smem + LDS_W2T + (g*16 + rS)*128 + ((ks*64 + q*16) ^ swzA));
        union { u32x4 u; s16x8 s; } hf;
        hf.u = (u32x4){ hc[4*g+2*ks][0], hc[4*g+2*ks][1],
                        hc[4*g+2*ks+1][0], hc[4*g+2*ks+1][1] };
        acc2[g] = __builtin_amdgcn_mfma_f32_16x16x32_bf16(
            af, hf.s, (ks==0) ? z : acc2[g], 0,0,0);
      }

    // --- epilogue2: lane q==0 holds a full row's 4 logits -> lane-local softmax ---
    if (q == 0){
      long row = base + u*16 + rS;
      int g = gb;
      f32x4 lv = acc2[0];
      lv = (g==1) ? acc2[1] : lv;
      lv = (g==2) ? acc2[2] : lv;
      lv = (g==3) ? acc2[3] : lv;
      f32x4 bs = *(const f32x4*)(b2);
      bs = (g==1) ? *(const f32x4*)(b2+4)  : bs;
      bs = (g==2) ? *(const f32x4*)(b2+8)  : bs;
      bs = (g==3) ? *(const f32x4*)(b2+12) : bs;
      f32x4 li;
#pragma unroll
      for (int p=0;p<4;++p){
        unsigned fe = mshift ? mb[p] : ((mb[0] >> (8*p)) & 0xffu);
        li[p] = fe ? (lv[p] + bs[p]) : -1e9f;
      }
      float m = fmaxf(fmaxf(li[0],li[1]), fmaxf(li[2],li[3]));
      f32x4 e;
#pragma unroll
      for (int p=0;p<4;++p) e[p] = __expf(li[p] - m);
      float inv = 1.0f / (e[0]+e[1]+e[2]+e[3]);
      f32x4 o;
#pragma unroll
      for (int p=0;p<4;++p) o[p] = e[p] * inv;
      *(f32x4*)(out + row*4) = o;

      // prefetch next unit's gids/mask (used at next iteration's softmax)
      if (u < 7){
        long nrow = row + 16;
        gb = gids[(size_t)nrow << gshift];
        if (mshift) mb = *(const u32x4*)(fmask + nrow*16);
        else        mb[0] = *(const unsigned*)(fmask + nrow*4);
      }
    }
  }
}

extern "C" void kernel_launch(void* const* d_in, const int* in_sizes, int n_in,
                              void* d_out, int out_size, void* d_ws, size_t ws_size,
                              hipStream_t stream){
  const float* X  = (const float*)d_in[0];
  const void*  gi = d_in[1];
  const void*  fm = d_in[2];
  const float* W1 = (const float*)d_in[3];
  const float* b1 = (const float*)d_in[4];
  const float* W2 = (const float*)d_in[5];
  const float* b2 = (const float*)d_in[6];
  unsigned char* ws = (unsigned char*)d_ws;
  float* out = (float*)d_out;

  prep_kernel<<<dim3(17), dim3(256), 0, stream>>>(W1, W2, gi, fm, ws);
  actor_kernel<<<dim3(512), dim3(256), 0, stream>>>(X, (const int*)gi,
                                                    (const unsigned char*)fm,
                                                    b1, b2, ws, out);
}

// Round 5
// 167.310 us; speedup vs baseline: 1.8236x; 1.2815x over previous
//
#include <hip/hip_runtime.h>
#include <hip/hip_bf16.h>
#include <cstdint>

#define NROWS 262144
#define DIM 128

typedef float f32x4 __attribute__((ext_vector_type(4)));
typedef short s16x8 __attribute__((ext_vector_type(8)));
typedef unsigned short u16x8 __attribute__((ext_vector_type(8)));
typedef unsigned int u32x4 __attribute__((ext_vector_type(4)));

__device__ __forceinline__ unsigned short cvbf(float f){
  unsigned u = __float_as_uint(f);
  return (unsigned short)((u + 0x8000u) >> 16);
}

__device__ __forceinline__ void ldsload16(const void* gp, void* lp){
  __builtin_amdgcn_global_load_lds((const __attribute__((address_space(1))) void*)gp,
                                   (__attribute__((address_space(3))) void*)lp,
                                   16, 0, 0);
}

// ---------------- prep kernel: weight repack + dtype detect into d_ws ----------------
// ws[0..65536): W1T bf16, row n=g*64+h (256 x 256B), byte = n*256 + (k*2 ^ ((n&7)<<4))
// ws[65536..73728): W2T bf16, row t=g*16+p (64 x 128B); element slot e (=ks*32+q*8+j)
//   holds W2[g][h(e)][p], h(e) = (e&32)|((e&4)<<2)|((e>>1)&12)|(e&3)  (k-slot permutation
//   matching GEMM1's C^T fragment layout -> GEMM2 needs no hidden transpose), p>=4 zeros.
// ws[73728]: gshift (0=int32 gids, 1=int64) ; ws[73732]: mshift (0=byte mask, 2=int32 mask)
__global__ void prep_kernel(const float* __restrict__ W1, const float* __restrict__ W2,
                            const void* __restrict__ gids_raw, const void* __restrict__ mask_raw,
                            unsigned char* __restrict__ ws){
  int tid = threadIdx.x, bid = blockIdx.x;
  if (bid < 16){
    int chunk = bid*256 + tid;
    int n    = chunk >> 4;
    int kb16 = chunk & 15;
    int d0   = kb16 * 8;
    int g = n >> 6, h = n & 63;
    u16x8 v;
#pragma unroll
    for (int j=0;j<8;++j) v[j] = cvbf(W1[((g*DIM) + d0 + j)*64 + h]);
    unsigned off = (unsigned)n*256 + (((unsigned)kb16*16) ^ (((unsigned)(n&7))<<4));
    *(u16x8*)(ws + off) = v;
  } else {
#pragma unroll
    for (int i=0;i<16;++i){
      int el = tid + i*256;          // 0..4095 elements of W2T
      int t  = el >> 6;              // row t = g*16+p
      int e  = el & 63;              // k-slot within row
      int g = t >> 4, p = t & 15;
      int h = (e & 32) | ((e & 4) << 2) | ((e >> 1) & 12) | (e & 3);
      float f = (p < 4) ? W2[(g*64 + h)*4 + p] : 0.0f;
      unsigned off = 65536u + (unsigned)t*128 + (((unsigned)(e*2)) ^ (((unsigned)(t&7))<<4));
      *(unsigned short*)(ws + off) = cvbf(f);
    }
    if (tid < 64){
      const int* g32 = (const int*)gids_raw;
      int accg = 0;
#pragma unroll
      for (int i=0;i<8;++i) accg |= g32[(tid*8 + i)*2 + 1];
      const unsigned char* m8 = (const unsigned char*)mask_raw;
      int accm = 0;
#pragma unroll
      for (int i=0;i<16;++i){
        int off = tid*16 + i;
        if (off & 3) accm |= m8[off];
      }
      unsigned long long bg = __ballot(accg != 0);
      unsigned long long bm = __ballot(accm != 0);
      if (tid == 0){
        *(int*)(ws + 73728) = (bg == 0ull) ? 1 : 0;
        *(int*)(ws + 73732) = (bm == 0ull) ? 2 : 0;
      }
    }
  }
}

// ---------------- main kernel: persistent, pair-fused, low-pressure ----------------
#define LDS_W2T 65536
#define LDS_B1  (65536+8192)
#define LDS_TOTAL (65536+8192+1024)

__global__ __launch_bounds__(256, 2)
void actor_kernel(const float* __restrict__ X, const int* __restrict__ gids,
                  const unsigned char* __restrict__ fmask,
                  const float* __restrict__ b1, const float* __restrict__ b2,
                  const unsigned char* __restrict__ ws, float* __restrict__ out){
  __shared__ char smem[LDS_TOTAL];
  const int tid  = threadIdx.x;
  const int wave = tid >> 6, lane = tid & 63;
  const int q    = lane >> 4, rS = lane & 15;
  const int swzA = (rS & 7) << 4;

  const int gshift = *(const int*)(ws + 73728);
  const int mshift = *(const int*)(ws + 73732);

  // --- stage weights+b1 to LDS once per block ---
#pragma unroll
  for (int i=0;i<16;++i){
    int off = i*4096 + wave*1024;
    ldsload16(ws + off + lane*16, smem + off);
  }
#pragma unroll
  for (int i=0;i<2;++i){
    int off = i*4096 + wave*1024;
    ldsload16(ws + 65536 + off + lane*16, smem + LDS_W2T + off);
  }
  if (wave == 0)
    ldsload16((const unsigned char*)b1 + lane*16, smem + LDS_B1);

  const long base = (long)blockIdx.x * 512 + wave * 128;   // this wave's first row

  f32x4 xb[4][2];    // single-buffered X registers for one 16-row unit
  int   gb;
  u32x4 mb;

  // prologue: unit 0 loads (inline, no lambdas)
  {
    const float* xp = X + (base + rS) * DIM + q*8;
#pragma unroll
    for (int k=0;k<4;++k){
      xb[k][0] = *(const f32x4*)(xp + k*32);
      xb[k][1] = *(const f32x4*)(xp + k*32 + 4);
    }
    if (q == 0){
      long row = base + rS;
      gb = gids[(size_t)row << gshift];
      if (mshift) mb = *(const u32x4*)(fmask + row*16);
      else        mb[0] = *(const unsigned*)(fmask + row*4);
    }
  }
  __syncthreads();   // weights resident (also drains prologue loads)

  const f32x4 z = (f32x4){0.f,0.f,0.f,0.f};

#pragma unroll 1
  for (int u=0; u<8; ++u){
    // --- convert current unit's X to bf16 B-fragments (frees xb for prefetch) ---
    s16x8 bfr[4];
#pragma unroll
    for (int k=0;k<4;++k){
      s16x8 v;
#pragma unroll
      for (int j=0;j<4;++j){ v[j] = (short)cvbf(xb[k][0][j]); v[j+4] = (short)cvbf(xb[k][1][j]); }
      bfr[k] = v;
    }

    // --- prefetch next unit's X (in flight across all compute below) ---
    if (u < 7){
      const float* xp = X + (base + (u+1)*16 + rS) * DIM + q*8;
#pragma unroll
      for (int k=0;k<4;++k){
        xb[k][0] = *(const f32x4*)(xp + k*32);
        xb[k][1] = *(const f32x4*)(xp + k*32 + 4);
      }
    }

    // --- fused GEMM1 -> relu -> GEMM2, one mt-pair at a time (tiny live set) ---
    f32x4 acc2[4];
#pragma unroll
    for (int p=0;p<8;++p){
      f32x4 aA, aB;
#pragma unroll
      for (int k=0;k<4;++k){
        const s16x8 sA = *(const s16x8*)(smem + ((2*p  )*16 + rS)*256 + ((k*64 + q*16) ^ swzA));
        const s16x8 sB = *(const s16x8*)(smem + ((2*p+1)*16 + rS)*256 + ((k*64 + q*16) ^ swzA));
        aA = __builtin_amdgcn_mfma_f32_16x16x32_bf16(sA, bfr[k], (k==0)? z : aA, 0,0,0);
        aB = __builtin_amdgcn_mfma_f32_16x16x32_bf16(sB, bfr[k], (k==0)? z : aB, 0,0,0);
      }
      const f32x4 b1A = *(const f32x4*)(smem + LDS_B1 + (2*p  )*64 + q*16);
      const f32x4 b1B = *(const f32x4*)(smem + LDS_B1 + (2*p+1)*64 + q*16);
      f32x4 vA = aA + b1A;
      f32x4 vB = aB + b1B;
#pragma unroll
      for (int j=0;j<4;++j){
        vA[j] = vA[j] > 0.f ? vA[j] : 0.f;
        vB[j] = vB[j] > 0.f ? vB[j] : 0.f;
      }
      s16x8 hf;
#pragma unroll
      for (int j=0;j<4;++j){
        hf[j]   = (short)cvbf(vA[j]);
        hf[j+4] = (short)cvbf(vB[j]);
      }
      const s16x8 af = *(const s16x8*)(smem + LDS_W2T + ((p>>1)*16 + rS)*128
                                       + (((p&1)*64 + q*16) ^ swzA));
      acc2[p>>1] = __builtin_amdgcn_mfma_f32_16x16x32_bf16(
          af, hf, (p&1) ? acc2[p>>1] : z, 0,0,0);
    }

    // --- epilogue: lane q==0 holds a full row's 4 logits -> lane-local softmax ---
    if (q == 0){
      long row = base + u*16 + rS;
      int g = gb;
      f32x4 lv = acc2[0];
      lv = (g==1) ? acc2[1] : lv;
      lv = (g==2) ? acc2[2] : lv;
      lv = (g==3) ? acc2[3] : lv;
      f32x4 bs = *(const f32x4*)(b2);
      bs = (g==1) ? *(const f32x4*)(b2+4)  : bs;
      bs = (g==2) ? *(const f32x4*)(b2+8)  : bs;
      bs = (g==3) ? *(const f32x4*)(b2+12) : bs;
      f32x4 li;
#pragma unroll
      for (int p=0;p<4;++p){
        unsigned fe = mshift ? mb[p] : ((mb[0] >> (8*p)) & 0xffu);
        li[p] = fe ? (lv[p] + bs[p]) : -1e9f;
      }
      float m = fmaxf(fmaxf(li[0],li[1]), fmaxf(li[2],li[3]));
      f32x4 e;
#pragma unroll
      for (int p=0;p<4;++p) e[p] = __expf(li[p] - m);
      float inv = 1.0f / (e[0]+e[1]+e[2]+e[3]);
      f32x4 o;
#pragma unroll
      for (int p=0;p<4;++p) o[p] = e[p] * inv;
      *(f32x4*)(out + row*4) = o;

      // prefetch next unit's gids/mask
      if (u < 7){
        long nrow = row + 16;
        gb = gids[(size_t)nrow << gshift];
        if (mshift) mb = *(const u32x4*)(fmask + nrow*16);
        else        mb[0] = *(const unsigned*)(fmask + nrow*4);
      }
    }
  }
}

extern "C" void kernel_launch(void* const* d_in, const int* in_sizes, int n_in,
                              void* d_out, int out_size, void* d_ws, size_t ws_size,
                              hipStream_t stream){
  const float* X  = (const float*)d_in[0];
  const void*  gi = d_in[1];
  const void*  fm = d_in[2];
  const float* W1 = (const float*)d_in[3];
  const float* b1 = (const float*)d_in[4];
  const float* W2 = (const float*)d_in[5];
  const float* b2 = (const float*)d_in[6];
  unsigned char* ws = (unsigned char*)d_ws;
  float* out = (float*)d_out;

  prep_kernel<<<dim3(17), dim3(256), 0, stream>>>(W1, W2, gi, fm, ws);
  actor_kernel<<<dim3(512), dim3(256), 0, stream>>>(X, (const int*)gi,
                                                    (const unsigned char*)fm,
                                                    b1, b2, ws, out);
}

// Round 6
// 131.729 us; speedup vs baseline: 2.3162x; 1.2701x over previous
//
#include <hip/hip_runtime.h>
#include <hip/hip_bf16.h>
#include <cstdint>

#define NROWS 262144
#define DIM 128

typedef float f32x4 __attribute__((ext_vector_type(4)));
typedef short s16x8 __attribute__((ext_vector_type(8)));
typedef unsigned short u16x8 __attribute__((ext_vector_type(8)));
typedef unsigned int u32x4 __attribute__((ext_vector_type(4)));

__device__ __forceinline__ unsigned short cvbf(float f){
  unsigned u = __float_as_uint(f);
  return (unsigned short)((u + 0x8000u) >> 16);
}

__device__ __forceinline__ void ldsload16(const void* gp, void* lp){
  __builtin_amdgcn_global_load_lds((const __attribute__((address_space(1))) void*)gp,
                                   (__attribute__((address_space(3))) void*)lp,
                                   16, 0, 0);
}

// ---------------- prep kernel: weight repack + dtype detect into d_ws ----------------
// ws[0..65536): W1T bf16, row n=g*64+h (256 x 256B), byte = n*256 + (k*2 ^ ((n&7)<<4))
// ws[65536..73728): W2T bf16, row t=g*16+p (64 x 128B); element slot e (=ks*32+q*8+j)
//   holds W2[g][h(e)][p], h(e) = (e&32)|((e&4)<<2)|((e>>1)&12)|(e&3)  (k-slot permutation
//   matching GEMM1's C^T fragment layout -> GEMM2 needs no hidden transpose), p>=4 zeros.
// ws[73728]: gshift (0=int32 gids, 1=int64) ; ws[73732]: mshift (0=byte mask, 2=int32 mask)
__global__ void prep_kernel(const float* __restrict__ W1, const float* __restrict__ W2,
                            const void* __restrict__ gids_raw, const void* __restrict__ mask_raw,
                            unsigned char* __restrict__ ws){
  int tid = threadIdx.x, bid = blockIdx.x;
  if (bid < 16){
    int chunk = bid*256 + tid;
    int n    = chunk >> 4;
    int kb16 = chunk & 15;
    int d0   = kb16 * 8;
    int g = n >> 6, h = n & 63;
    u16x8 v;
#pragma unroll
    for (int j=0;j<8;++j) v[j] = cvbf(W1[((g*DIM) + d0 + j)*64 + h]);
    unsigned off = (unsigned)n*256 + (((unsigned)kb16*16) ^ (((unsigned)(n&7))<<4));
    *(u16x8*)(ws + off) = v;
  } else {
#pragma unroll
    for (int i=0;i<16;++i){
      int el = tid + i*256;          // 0..4095 elements of W2T
      int t  = el >> 6;              // row t = g*16+p
      int e  = el & 63;              // k-slot within row
      int g = t >> 4, p = t & 15;
      int h = (e & 32) | ((e & 4) << 2) | ((e >> 1) & 12) | (e & 3);
      float f = (p < 4) ? W2[(g*64 + h)*4 + p] : 0.0f;
      unsigned off = 65536u + (unsigned)t*128 + (((unsigned)(e*2)) ^ (((unsigned)(t&7))<<4));
      *(unsigned short*)(ws + off) = cvbf(f);
    }
    if (tid < 64){
      const int* g32 = (const int*)gids_raw;
      int accg = 0;
#pragma unroll
      for (int i=0;i<8;++i) accg |= g32[(tid*8 + i)*2 + 1];
      const unsigned char* m8 = (const unsigned char*)mask_raw;
      int accm = 0;
#pragma unroll
      for (int i=0;i<16;++i){
        int off = tid*16 + i;
        if (off & 3) accm |= m8[off];
      }
      unsigned long long bg = __ballot(accg != 0);
      unsigned long long bm = __ballot(accm != 0);
      if (tid == 0){
        *(int*)(ws + 73728) = (bg == 0ull) ? 1 : 0;
        *(int*)(ws + 73732) = (bm == 0ull) ? 2 : 0;
      }
    }
  }
}

// ---------------- main kernel: persistent, carry-free units, pure-TLP hiding ----------------
#define LDS_W2T 65536
#define LDS_TOTAL (65536+8192)

__global__ __launch_bounds__(256, 2)
void actor_kernel(const float* __restrict__ X, const int* __restrict__ gids,
                  const unsigned char* __restrict__ fmask,
                  const float* __restrict__ b1, const float* __restrict__ b2,
                  const unsigned char* __restrict__ ws, float* __restrict__ out){
  __shared__ char smem[LDS_TOTAL];
  const int tid  = threadIdx.x;
  const int wave = tid >> 6, lane = tid & 63;
  const int q    = lane >> 4, rS = lane & 15;
  const int swzA = (rS & 7) << 4;

  const int gshift = *(const int*)(ws + 73728);
  const int mshift = *(const int*)(ws + 73732);

  // --- stage W1T + W2T to LDS once per block ---
#pragma unroll
  for (int i=0;i<16;++i){
    int off = i*4096 + wave*1024;
    ldsload16(ws + off + lane*16, smem + off);
  }
#pragma unroll
  for (int i=0;i<2;++i){
    int off = i*4096 + wave*1024;
    ldsload16(ws + 65536 + off + lane*16, smem + LDS_W2T + off);
  }
  __syncthreads();

  // --- hoist W2T A-fragments (unit-invariant) into registers ---
  s16x8 af[8];
#pragma unroll
  for (int p=0;p<8;++p)
    af[p] = *(const s16x8*)(smem + LDS_W2T + ((p>>1)*16 + rS)*128
                            + (((p&1)*64 + q*16) ^ swzA));

  const long base = (long)blockIdx.x * 512 + wave * 128;
  const f32x4 z = (f32x4){0.f,0.f,0.f,0.f};

#pragma unroll 1
  for (int u=0; u<8; ++u){
    const long row = base + u*16 + rS;

    // --- load this unit's X rows (dies after cvt; no carries across iterations) ---
    f32x4 xb[4][2];
    {
      const float* xp = X + row * DIM + q*8;
#pragma unroll
      for (int k=0;k<4;++k){
        xb[k][0] = *(const f32x4*)(xp + k*32);
        xb[k][1] = *(const f32x4*)(xp + k*32 + 4);
      }
    }
    // --- gid + mask, all lanes (uniform per rS, no divergence) ---
    int gb = gids[(size_t)row << gshift];
    u32x4 mb;
    if (mshift){
      mb = *(const u32x4*)(fmask + row*16);
    } else {
      unsigned w = *(const unsigned*)(fmask + row*4);
      mb[0] = w & 0xffu; mb[1] = (w>>8) & 0xffu; mb[2] = (w>>16) & 0xffu; mb[3] = w>>24;
    }

    // --- convert X to bf16 B-fragments ---
    s16x8 bfr[4];
#pragma unroll
    for (int k=0;k<4;++k){
      s16x8 v;
#pragma unroll
      for (int j=0;j<4;++j){ v[j] = (short)cvbf(xb[k][0][j]); v[j+4] = (short)cvbf(xb[k][1][j]); }
      bfr[k] = v;
    }

    // --- fused GEMM1 -> +b1/relu -> GEMM2, one mt-pair at a time ---
    f32x4 acc2[4];
#pragma unroll
    for (int p=0;p<8;++p){
      f32x4 aA, aB;
#pragma unroll
      for (int k=0;k<4;++k){
        const s16x8 sA = *(const s16x8*)(smem + ((2*p  )*16 + rS)*256 + ((k*64 + q*16) ^ swzA));
        const s16x8 sB = *(const s16x8*)(smem + ((2*p+1)*16 + rS)*256 + ((k*64 + q*16) ^ swzA));
        aA = __builtin_amdgcn_mfma_f32_16x16x32_bf16(sA, bfr[k], (k==0)? z : aA, 0,0,0);
        aB = __builtin_amdgcn_mfma_f32_16x16x32_bf16(sB, bfr[k], (k==0)? z : aB, 0,0,0);
      }
      // b1 fragment layout is linear b1: floats [mt*16 + q*4 .. +3]  (L1-resident)
      const f32x4 b1A = *(const f32x4*)(b1 + p*32 + q*4);
      const f32x4 b1B = *(const f32x4*)(b1 + p*32 + 16 + q*4);
      f32x4 vA = aA + b1A;
      f32x4 vB = aB + b1B;
#pragma unroll
      for (int j=0;j<4;++j){
        vA[j] = vA[j] > 0.f ? vA[j] : 0.f;
        vB[j] = vB[j] > 0.f ? vB[j] : 0.f;
      }
      s16x8 hf;
#pragma unroll
      for (int j=0;j<4;++j){
        hf[j]   = (short)cvbf(vA[j]);
        hf[j+4] = (short)cvbf(vB[j]);
      }
      acc2[p>>1] = __builtin_amdgcn_mfma_f32_16x16x32_bf16(
          af[p], hf, (p&1) ? acc2[p>>1] : z, 0,0,0);
    }

    // --- epilogue: all lanes compute (q>0 hold zero-pad rows), q==0 stores ---
    {
      int g = gb;
      f32x4 lv = acc2[0];
      lv = (g==1) ? acc2[1] : lv;
      lv = (g==2) ? acc2[2] : lv;
      lv = (g==3) ? acc2[3] : lv;
      const f32x4 bs = *(const f32x4*)(b2 + g*4);   // one indexed 16B load, L1-resident
      f32x4 li;
#pragma unroll
      for (int p=0;p<4;++p)
        li[p] = mb[p] ? (lv[p] + bs[p]) : -1e9f;
      float m = fmaxf(fmaxf(li[0],li[1]), fmaxf(li[2],li[3]));
      f32x4 e;
#pragma unroll
      for (int p=0;p<4;++p) e[p] = __expf(li[p] - m);
      float inv = 1.0f / (e[0]+e[1]+e[2]+e[3]);
      f32x4 o;
#pragma unroll
      for (int p=0;p<4;++p) o[p] = e[p] * inv;
      if (q == 0)
        *(f32x4*)(out + row*4) = o;
    }
  }
}

extern "C" void kernel_launch(void* const* d_in, const int* in_sizes, int n_in,
                              void* d_out, int out_size, void* d_ws, size_t ws_size,
                              hipStream_t stream){
  const float* X  = (const float*)d_in[0];
  const void*  gi = d_in[1];
  const void*  fm = d_in[2];
  const float* W1 = (const float*)d_in[3];
  const float* b1 = (const float*)d_in[4];
  const float* W2 = (const float*)d_in[5];
  const float* b2 = (const float*)d_in[6];
  unsigned char* ws = (unsigned char*)d_ws;
  float* out = (float*)d_out;

  prep_kernel<<<dim3(17), dim3(256), 0, stream>>>(W1, W2, gi, fm, ws);
  actor_kernel<<<dim3(512), dim3(256), 0, stream>>>(X, (const int*)gi,
                                                    (const unsigned char*)fm,
                                                    b1, b2, ws, out);
}

// Round 7
// 40.397 us; speedup vs baseline: 7.5527x; 3.2608x over previous
//
#include <hip/hip_runtime.h>
#include <hip/hip_bf16.h>
#include <cstdint>

#define NROWS 262144
#define DIM 128

typedef float f32x4 __attribute__((ext_vector_type(4)));
typedef short s16x8 __attribute__((ext_vector_type(8)));
typedef unsigned short u16x8 __attribute__((ext_vector_type(8)));
typedef unsigned int u32x4 __attribute__((ext_vector_type(4)));

__device__ __forceinline__ unsigned short cvbf(float f){
  unsigned u = __float_as_uint(f);
  return (unsigned short)((u + 0x8000u) >> 16);
}

__device__ __forceinline__ void ldsload16(const void* gp, void* lp){
  __builtin_amdgcn_global_load_lds((const __attribute__((address_space(1))) void*)gp,
                                   (__attribute__((address_space(3))) void*)lp,
                                   16, 0, 0);
}

// ---------------- prep kernel: weight repack + dtype detect into d_ws ----------------
// ws[0..65536): W1T bf16, row n=g*64+h (256 x 256B), byte = n*256 + (k*2 ^ ((n&7)<<4))
// ws[65536..73728): W2T bf16, row t=g*16+p (64 x 128B); element slot e (=ks*32+q*8+j)
//   holds W2[g][h(e)][p], h(e) = (e&32)|((e&4)<<2)|((e>>1)&12)|(e&3)  (k-slot permutation
//   matching GEMM1's C^T fragment layout -> GEMM2 needs no hidden transpose), p>=4 zeros.
// ws[73728]: gshift (0=int32 gids, 1=int64) ; ws[73732]: mshift (0=byte mask, 2=int32 mask)
__global__ void prep_kernel(const float* __restrict__ W1, const float* __restrict__ W2,
                            const void* __restrict__ gids_raw, const void* __restrict__ mask_raw,
                            unsigned char* __restrict__ ws){
  int tid = threadIdx.x, bid = blockIdx.x;
  if (bid < 16){
    int chunk = bid*256 + tid;
    int n    = chunk >> 4;
    int kb16 = chunk & 15;
    int d0   = kb16 * 8;
    int g = n >> 6, h = n & 63;
    u16x8 v;
#pragma unroll
    for (int j=0;j<8;++j) v[j] = cvbf(W1[((g*DIM) + d0 + j)*64 + h]);
    unsigned off = (unsigned)n*256 + (((unsigned)kb16*16) ^ (((unsigned)(n&7))<<4));
    *(u16x8*)(ws + off) = v;
  } else {
#pragma unroll
    for (int i=0;i<16;++i){
      int el = tid + i*256;          // 0..4095 elements of W2T
      int t  = el >> 6;              // row t = g*16+p
      int e  = el & 63;              // k-slot within row
      int g = t >> 4, p = t & 15;
      int h = (e & 32) | ((e & 4) << 2) | ((e >> 1) & 12) | (e & 3);
      float f = (p < 4) ? W2[(g*64 + h)*4 + p] : 0.0f;
      unsigned off = 65536u + (unsigned)t*128 + (((unsigned)(e*2)) ^ (((unsigned)(t&7))<<4));
      *(unsigned short*)(ws + off) = cvbf(f);
    }
    if (tid < 64){
      const int* g32 = (const int*)gids_raw;
      int accg = 0;
#pragma unroll
      for (int i=0;i<8;++i) accg |= g32[(tid*8 + i)*2 + 1];
      const unsigned char* m8 = (const unsigned char*)mask_raw;
      int accm = 0;
#pragma unroll
      for (int i=0;i<16;++i){
        int off = tid*16 + i;
        if (off & 3) accm |= m8[off];
      }
      unsigned long long bg = __ballot(accg != 0);
      unsigned long long bm = __ballot(accm != 0);
      if (tid == 0){
        *(int*)(ws + 73728) = (bg == 0ull) ? 1 : 0;
        *(int*)(ws + 73732) = (bm == 0ull) ? 2 : 0;
      }
    }
  }
}

// ---------------- main kernel: persistent, carry-free units, pinned schedule ----------------
#define LDS_W2T 65536
#define LDS_B1  (65536+8192)
#define LDS_TOTAL (65536+8192+1024)

__global__ __launch_bounds__(256, 2)
void actor_kernel(const float* __restrict__ X, const int* __restrict__ gids,
                  const unsigned char* __restrict__ fmask,
                  const float* __restrict__ b1, const float* __restrict__ b2,
                  const unsigned char* __restrict__ ws, float* __restrict__ out){
  __shared__ char smem[LDS_TOTAL];
  const int tid  = threadIdx.x;
  const int wave = tid >> 6, lane = tid & 63;
  const int q    = lane >> 4, rS = lane & 15;
  const int swzA = (rS & 7) << 4;

  const int gshift = *(const int*)(ws + 73728);
  const int mshift = *(const int*)(ws + 73732);

  // --- stage W1T + W2T + b1 to LDS once per block ---
#pragma unroll
  for (int i=0;i<16;++i){
    int off = i*4096 + wave*1024;
    ldsload16(ws + off + lane*16, smem + off);
  }
#pragma unroll
  for (int i=0;i<2;++i){
    int off = i*4096 + wave*1024;
    ldsload16(ws + 65536 + off + lane*16, smem + LDS_W2T + off);
  }
  if (wave == 0)
    ldsload16((const unsigned char*)b1 + lane*16, smem + LDS_B1);
  __syncthreads();

  const long base = (long)blockIdx.x * 512 + wave * 128;
  const f32x4 z = (f32x4){0.f,0.f,0.f,0.f};

#pragma unroll 1
  for (int u=0; u<8; ++u){
    const long row = base + u*16 + rS;

    // --- load this unit's X rows (dies after cvt; no carries across iterations) ---
    f32x4 xb[4][2];
    {
      const float* xp = X + row * DIM + q*8;
#pragma unroll
      for (int k=0;k<4;++k){
        xb[k][0] = *(const f32x4*)(xp + k*32);
        xb[k][1] = *(const f32x4*)(xp + k*32 + 4);
      }
    }
    // --- gid + mask, all lanes (uniform per rS, no divergence) ---
    int gb = gids[(size_t)row << gshift];
    u32x4 mb;
    if (mshift){
      mb = *(const u32x4*)(fmask + row*16);
    } else {
      unsigned w = *(const unsigned*)(fmask + row*4);
      mb[0] = w & 0xffu; mb[1] = (w>>8) & 0xffu; mb[2] = (w>>16) & 0xffu; mb[3] = w>>24;
    }

    // --- convert X to bf16 B-fragments ---
    s16x8 bfr[4];
#pragma unroll
    for (int k=0;k<4;++k){
      s16x8 v;
#pragma unroll
      for (int j=0;j<4;++j){ v[j] = (short)cvbf(xb[k][0][j]); v[j+4] = (short)cvbf(xb[k][1][j]); }
      bfr[k] = v;
    }

    // fence: nothing from the p-loop may be hoisted above this point
    __builtin_amdgcn_sched_barrier(0);

    // --- fused GEMM1 -> +b1/relu -> GEMM2, one mt-pair at a time, schedule pinned per p ---
    f32x4 acc2[4];
#pragma unroll
    for (int p=0;p<8;++p){
      f32x4 aA, aB;
#pragma unroll
      for (int k=0;k<4;++k){
        const s16x8 sA = *(const s16x8*)(smem + ((2*p  )*16 + rS)*256 + ((k*64 + q*16) ^ swzA));
        const s16x8 sB = *(const s16x8*)(smem + ((2*p+1)*16 + rS)*256 + ((k*64 + q*16) ^ swzA));
        aA = __builtin_amdgcn_mfma_f32_16x16x32_bf16(sA, bfr[k], (k==0)? z : aA, 0,0,0);
        aB = __builtin_amdgcn_mfma_f32_16x16x32_bf16(sB, bfr[k], (k==0)? z : aB, 0,0,0);
      }
      const f32x4 b1A = *(const f32x4*)(smem + LDS_B1 + (2*p  )*64 + q*16);
      const f32x4 b1B = *(const f32x4*)(smem + LDS_B1 + (2*p+1)*64 + q*16);
      f32x4 vA = aA + b1A;
      f32x4 vB = aB + b1B;
#pragma unroll
      for (int j=0;j<4;++j){
        vA[j] = vA[j] > 0.f ? vA[j] : 0.f;
        vB[j] = vB[j] > 0.f ? vB[j] : 0.f;
      }
      s16x8 hf;
#pragma unroll
      for (int j=0;j<4;++j){
        hf[j]   = (short)cvbf(vA[j]);
        hf[j+4] = (short)cvbf(vB[j]);
      }
      const s16x8 af = *(const s16x8*)(smem + LDS_W2T + ((p>>1)*16 + rS)*128
                                       + (((p&1)*64 + q*16) ^ swzA));
      acc2[p>>1] = __builtin_amdgcn_mfma_f32_16x16x32_bf16(
          af, hf, (p&1) ? acc2[p>>1] : z, 0,0,0);
      // pin: loads of p+1 may not be hoisted above this point
      __builtin_amdgcn_sched_barrier(0);
    }

    // --- epilogue: all lanes compute, q==0 stores ---
    {
      int g = gb;
      f32x4 lv = acc2[0];
      lv = (g==1) ? acc2[1] : lv;
      lv = (g==2) ? acc2[2] : lv;
      lv = (g==3) ? acc2[3] : lv;
      const f32x4 bs = *(const f32x4*)(b2 + g*4);   // one indexed 16B load, L1-resident
      f32x4 li;
#pragma unroll
      for (int p=0;p<4;++p)
        li[p] = mb[p] ? (lv[p] + bs[p]) : -1e9f;
      float m = fmaxf(fmaxf(li[0],li[1]), fmaxf(li[2],li[3]));
      f32x4 e;
#pragma unroll
      for (int p=0;p<4;++p) e[p] = __expf(li[p] - m);
      float inv = 1.0f / (e[0]+e[1]+e[2]+e[3]);
      f32x4 o;
#pragma unroll
      for (int p=0;p<4;++p) o[p] = e[p] * inv;
      if (q == 0)
        *(f32x4*)(out + row*4) = o;
    }
  }
}

extern "C" void kernel_launch(void* const* d_in, const int* in_sizes, int n_in,
                              void* d_out, int out_size, void* d_ws, size_t ws_size,
                              hipStream_t stream){
  const float* X  = (const float*)d_in[0];
  const void*  gi = d_in[1];
  const void*  fm = d_in[2];
  const float* W1 = (const float*)d_in[3];
  const float* b1 = (const float*)d_in[4];
  const float* W2 = (const float*)d_in[5];
  const float* b2 = (const float*)d_in[6];
  unsigned char* ws = (unsigned char*)d_ws;
  float* out = (float*)d_out;

  prep_kernel<<<dim3(17), dim3(256), 0, stream>>>(W1, W2, gi, fm, ws);
  actor_kernel<<<dim3(512), dim3(256), 0, stream>>>(X, (const int*)gi,
                                                    (const unsigned char*)fm,
                                                    b1, b2, ws, out);
}